// Round 9
// baseline (13.364 us; speedup 1.0000x reference)
//
#include <hip/hip_runtime.h>
#include <hip/hip_bf16.h>
#include <stdint.h>

#define I_DIM   256
#define O_DIM   256
#define NCH     8      // K chunks: BK=128 (=32 i-values) each

typedef float f32x4 __attribute__((ext_vector_type(4)));
typedef short bf16x8 __attribute__((ext_vector_type(8)));

// pack 2 f32 -> u32 of 2 bf16 (RNE); compiler emits v_cvt_pk_bf16_f32
__device__ __forceinline__ uint32_t pk2(float a, float b) {
    __hip_bfloat162 h = __float22bfloat162_rn(make_float2(a, b));
    uint32_t u;
    __builtin_memcpy(&u, &h, 4);
    return u;
}

// T0..T3 of tanh(v): lo = {T0=1, T1=t}, hi = {T2, T3}
// (clip dropped: tanh<1 in f32 below ~9 sigma; even t==1 is within 5e-7 of ref)
__device__ __forceinline__ void basis2(float v, uint32_t& lo, uint32_t& hi) {
    float e = __expf(2.0f * v);
    float t = 1.0f - 2.0f / (e + 1.0f);
    float t2 = __builtin_fmaf(2.0f * t, t, -1.0f);
    float t3 = __builtin_fmaf(2.0f * t, t2, -t);
    lo = pk2(1.0f, t);
    hi = pk2(t2, t3);
}

// Tile BM=16 x BN=64, BK=128, double-buffered, LDS 40KB -> 4 blocks/CU.
// Basis redundancy 256/BN = 4 (halved vs R7) -> trans-pipe work halved.
// A[s]: s*4096 + row*256 + kbyte          (rows 0..15)   2x4KB
// B[s]: 8192 + s*16384 + col*256 + kbyte  (cols 0..63)   2x16KB
// XOR swizzle ^((row&15)<<4): frag reads 2 lanes/bank (free, m136)
__global__ __launch_bounds__(256, 4) void cheby_mfma(
        const float* __restrict__ x, const float* __restrict__ cc,
        float* __restrict__ out) {
    __shared__ __align__(16) unsigned char lds[40960];

    const int tid  = threadIdx.x;
    const int lane = tid & 63;
    const int wid  = tid >> 6;          // 0..3 = output column quadrant
    const int bm   = blockIdx.x >> 2;   // 128 M-tiles
    const int bn   = blockIdx.x & 3;    // 4 N-tiles
    const int m0   = bm * 16;
    const int n0   = bn * 64;

    const int arow = tid >> 4;          // 0..15  A row
    const int apos = tid & 15;          // 0..15  which float2 of x in chunk
    const int bcl  = tid & 63;          // 0..63  B col
    const int big  = tid >> 6;          // 0..3   group of 8 i's

    const float2* __restrict__ x2 = reinterpret_cast<const float2*>(x);
    const float4* __restrict__ c4 = reinterpret_cast<const float4*>(cc);

    // parity-named prefetch sets; indices compile-time via full unroll
    float2 ax[2];
    float4 cb[2][8];

    auto loadAB = [&](int ch, int s) {
        ax[s] = x2[(m0 + arow) * (I_DIM / 2) + ch * 16 + apos];
        #pragma unroll
        for (int j = 0; j < 8; ++j)
            cb[s][j] = c4[(ch * 32 + big * 8 + j) * O_DIM + n0 + bcl];
    };

    auto stageAB = [&](int s) {
        // A: 2 x-values -> 8 bf16 -> 1 swizzled uint4 write
        const uint32_t abase = (uint32_t)(s * 4096 + arow * 256 + apos * 16);
        const uint32_t axr   = (uint32_t)((arow & 15) << 4);
        uint32_t w0, w1, w2, w3;
        basis2(ax[s].x, w0, w1);
        basis2(ax[s].y, w2, w3);
        *reinterpret_cast<uint4*>(lds + (abase ^ axr)) = make_uint4(w0, w1, w2, w3);
        // B: 8 float4 (i = big*8+j, 4 d each) -> 4 swizzled uint4 writes
        const uint32_t bbase = (uint32_t)(8192 + s * 16384 + bcl * 256 + big * 64);
        const uint32_t bxr   = (uint32_t)((bcl & 15) << 4);
        #pragma unroll
        for (int j = 0; j < 8; j += 2) {
            uint32_t u0 = pk2(cb[s][j].x,     cb[s][j].y);
            uint32_t u1 = pk2(cb[s][j].z,     cb[s][j].w);
            uint32_t u2 = pk2(cb[s][j + 1].x, cb[s][j + 1].y);
            uint32_t u3 = pk2(cb[s][j + 1].z, cb[s][j + 1].w);
            *reinterpret_cast<uint4*>(lds + ((bbase + j * 8) ^ bxr)) = make_uint4(u0, u1, u2, u3);
        }
    };

    // 4 waves: wave wid owns 16x16 quadrant at column wid*16
    const int mrow  = lane & 15;              // 0..15
    const int bcol  = wid * 16 + (lane & 15); // 0..63
    const int klane = (lane >> 4) << 3;
    const uint32_t aswz = (uint32_t)((mrow & 15) << 4);
    const uint32_t bswz = (uint32_t)((bcol & 15) << 4);

    f32x4 acc0 = {0.f, 0.f, 0.f, 0.f};
    f32x4 acc1 = {0.f, 0.f, 0.f, 0.f};

    loadAB(0, 0);
    #pragma unroll
    for (int ch = 0; ch < NCH; ++ch) {
        const int s = ch & 1;
        if (ch + 1 < NCH) loadAB(ch + 1, s ^ 1);  // T14: issue before stage VALU
        stageAB(s);
        // single barrier per chunk (R7-verified with double buffering)
        __syncthreads();
        const uint32_t abase = (uint32_t)(s * 4096 + mrow * 256);
        const uint32_t bbase = (uint32_t)(8192 + s * 16384 + bcol * 256);
        __builtin_amdgcn_s_setprio(1);
        #pragma unroll
        for (int ks = 0; ks < 4; ++ks) {
            const uint32_t kb = (uint32_t)((ks * 32 + klane) * 2);
            bf16x8 a = *reinterpret_cast<const bf16x8*>(lds + ((abase + kb) ^ aswz));
            bf16x8 b = *reinterpret_cast<const bf16x8*>(lds + ((bbase + kb) ^ bswz));
            if (ks & 1) acc1 = __builtin_amdgcn_mfma_f32_16x16x32_bf16(a, b, acc1, 0, 0, 0);
            else        acc0 = __builtin_amdgcn_mfma_f32_16x16x32_bf16(a, b, acc0, 0, 0, 0);
        }
        __builtin_amdgcn_s_setprio(0);
    }

    // C/D layout: col=lane&15, row=(lane>>4)*4+reg [m89-verified, passing since R1]
    const float sc = 1.0f / 256.0f;
    f32x4 r = acc0 + acc1;
    const int gr = m0 + ((lane >> 4) << 2);
    const int gc = n0 + wid * 16 + (lane & 15);
    #pragma unroll
    for (int q = 0; q < 4; ++q)
        out[(gr + q) * O_DIM + gc] = r[q] * sc;
}

extern "C" void kernel_launch(void* const* d_in, const int* in_sizes, int n_in,
                              void* d_out, int out_size, void* d_ws, size_t ws_size,
                              hipStream_t stream) {
    (void)in_sizes; (void)n_in; (void)out_size; (void)d_ws; (void)ws_size;
    const float* x  = (const float*)d_in[0];
    const float* cc = (const float*)d_in[1];
    float* out = (float*)d_out;
    // 128 M-tiles x 4 N-tiles = 512 blocks, 256 threads (4 waves), 4 blocks/CU
    cheby_mfma<<<dim3(512), dim3(256), 0, stream>>>(x, cc, out);
}

// Round 10
// 12.747 us; speedup vs baseline: 1.0484x; 1.0484x over previous
//
#include <hip/hip_runtime.h>
#include <hip/hip_bf16.h>
#include <stdint.h>

#define I_DIM   256
#define O_DIM   256
#define NCH     4      // K chunks: BK=256 (=64 i-values) each

typedef float f32x4 __attribute__((ext_vector_type(4)));
typedef short bf16x8 __attribute__((ext_vector_type(8)));

// pack 2 f32 -> u32 of 2 bf16 (RNE); compiler emits v_cvt_pk_bf16_f32
__device__ __forceinline__ uint32_t pk2(float a, float b) {
    __hip_bfloat162 h = __float22bfloat162_rn(make_float2(a, b));
    uint32_t u;
    __builtin_memcpy(&u, &h, 4);
    return u;
}

// T0..T3 of tanh(v): lo = {T0=1, T1=t}, hi = {T2, T3}
// clip dropped: tanh<1 in f32 below ~9 sigma; even t=1.0 gives T_k(1)=1,
// within 5e-7 of ref's T_k(1-eps) -- far below bf16 rounding.
__device__ __forceinline__ void basis2(float v, uint32_t& lo, uint32_t& hi) {
    float e = __expf(2.0f * v);
    float t = 1.0f - 2.0f / (e + 1.0f);
    float t2 = __builtin_fmaf(2.0f * t, t, -1.0f);
    float t3 = __builtin_fmaf(2.0f * t, t2, -t);
    lo = pk2(1.0f, t);
    hi = pk2(t2, t3);
}

// LDS: A[s]: s*16384 + row*512 + kbyte ; B[s]: 32768 + s*16384 + col*512 + kbyte
// XOR-swizzled ^((row&31)<<4): frag reads 2-way (free), stage writes conflict-light
__global__ __launch_bounds__(256, 2) void cheby_mfma(
        const float* __restrict__ x, const float* __restrict__ cc,
        float* __restrict__ out) {
    __shared__ __align__(16) unsigned char lds[65536];

    const int tid  = threadIdx.x;
    const int lane = tid & 63;
    const int wid  = tid >> 6;
    const int bm   = blockIdx.x >> 3;   // 64 M-tiles
    const int bn   = blockIdx.x & 7;    // 8 N-tiles
    const int m0   = bm * 32;
    const int n0   = bn * 32;

    const int arow = tid >> 3;          // 0..31  A row
    const int aiq  = tid & 7;           // 0..7   pair of x-float4s
    const int bcl  = tid & 31;          // 0..31  B col
    const int big  = tid >> 5;          // 0..7   group of 8 i's

    const float4* __restrict__ x4 = reinterpret_cast<const float4*>(x);
    const float4* __restrict__ c4 = reinterpret_cast<const float4*>(cc);

    // parity-named prefetch sets; indices compile-time via full unroll
    float4 ax0[2], ax1[2], cb[2][8];

    auto loadAB = [&](int ch, int s) {
        const float4* p = &x4[(m0 + arow) * (I_DIM / 4) + ch * 16 + aiq * 2];
        ax0[s] = p[0]; ax1[s] = p[1];
        #pragma unroll
        for (int j = 0; j < 8; ++j)
            cb[s][j] = c4[(ch * 64 + big * 8 + j) * O_DIM + n0 + bcl];
    };

    auto stageAB = [&](int s) {
        const uint32_t abase = (uint32_t)(s * 16384 + arow * 512 + aiq * 64);
        const uint32_t axr   = (uint32_t)((arow & 31) << 4);
        uint32_t w0, w1, w2, w3, w4, w5, w6, w7;
        basis2(ax0[s].x, w0, w1); basis2(ax0[s].y, w2, w3);
        basis2(ax0[s].z, w4, w5); basis2(ax0[s].w, w6, w7);
        *reinterpret_cast<uint4*>(lds + ((abase     ) ^ axr)) = make_uint4(w0, w1, w2, w3);
        *reinterpret_cast<uint4*>(lds + ((abase + 16) ^ axr)) = make_uint4(w4, w5, w6, w7);
        basis2(ax1[s].x, w0, w1); basis2(ax1[s].y, w2, w3);
        basis2(ax1[s].z, w4, w5); basis2(ax1[s].w, w6, w7);
        *reinterpret_cast<uint4*>(lds + ((abase + 32) ^ axr)) = make_uint4(w0, w1, w2, w3);
        *reinterpret_cast<uint4*>(lds + ((abase + 48) ^ axr)) = make_uint4(w4, w5, w6, w7);
        const uint32_t bbase = (uint32_t)(32768 + s * 16384 + bcl * 512 + big * 64);
        const uint32_t bxr   = (uint32_t)((bcl & 31) << 4);
        #pragma unroll
        for (int j = 0; j < 8; j += 2) {
            uint32_t u0 = pk2(cb[s][j].x,     cb[s][j].y);
            uint32_t u1 = pk2(cb[s][j].z,     cb[s][j].w);
            uint32_t u2 = pk2(cb[s][j + 1].x, cb[s][j + 1].y);
            uint32_t u3 = pk2(cb[s][j + 1].z, cb[s][j + 1].w);
            *reinterpret_cast<uint4*>(lds + ((bbase + j * 8) ^ bxr)) = make_uint4(u0, u1, u2, u3);
        }
    };

    const int wr = wid >> 1, wc = wid & 1;
    const int mrow  = wr * 16 + (lane & 15);
    const int bcol  = wc * 16 + (lane & 15);
    const int klane = (lane >> 4) << 3;
    const uint32_t aswz = (uint32_t)((mrow & 31) << 4);
    const uint32_t bswz = (uint32_t)((bcol & 31) << 4);

    f32x4 acc0 = {0.f, 0.f, 0.f, 0.f};
    f32x4 acc1 = {0.f, 0.f, 0.f, 0.f};

    loadAB(0, 0);
    #pragma unroll
    for (int ch = 0; ch < NCH; ++ch) {
        const int s = ch & 1;
        if (ch + 1 < NCH) loadAB(ch + 1, s ^ 1);  // T14: issue before stage VALU
        stageAB(s);
        // ONE barrier per chunk: stage(ch+1) writes buf[(ch+1)&1], last read by
        // mfma(ch-1); this barrier at iter ch orders mfma(ch-1) -> stage(ch+1)
        // for every thread pair. Second barrier provably redundant.
        __syncthreads();
        const uint32_t abase = (uint32_t)(s * 16384 + mrow * 512);
        const uint32_t bbase = (uint32_t)(32768 + s * 16384 + bcol * 512);
        __builtin_amdgcn_s_setprio(1);
        #pragma unroll
        for (int ks = 0; ks < 8; ++ks) {
            const uint32_t kb = (uint32_t)((ks * 32 + klane) * 2);
            bf16x8 a = *reinterpret_cast<const bf16x8*>(lds + ((abase + kb) ^ aswz));
            bf16x8 b = *reinterpret_cast<const bf16x8*>(lds + ((bbase + kb) ^ bswz));
            if (ks & 1) acc1 = __builtin_amdgcn_mfma_f32_16x16x32_bf16(a, b, acc1, 0, 0, 0);
            else        acc0 = __builtin_amdgcn_mfma_f32_16x16x32_bf16(a, b, acc0, 0, 0, 0);
        }
        __builtin_amdgcn_s_setprio(0);
    }

    // C/D layout: col=lane&15, row=(lane>>4)*4+reg [m89-verified, passing since R1]
    const float sc = 1.0f / 256.0f;
    f32x4 r = acc0 + acc1;
    const int gr = m0 + wr * 16 + ((lane >> 4) << 2);
    const int gc = n0 + wc * 16 + (lane & 15);
    #pragma unroll
    for (int q = 0; q < 4; ++q)
        out[(gr + q) * O_DIM + gc] = r[q] * sc;
}

extern "C" void kernel_launch(void* const* d_in, const int* in_sizes, int n_in,
                              void* d_out, int out_size, void* d_ws, size_t ws_size,
                              hipStream_t stream) {
    (void)in_sizes; (void)n_in; (void)out_size; (void)d_ws; (void)ws_size;
    const float* x  = (const float*)d_in[0];
    const float* cc = (const float*)d_in[1];
    float* out = (float*)d_out;
    // 64 M-tiles x 8 N-tiles = 512 blocks, 256 threads (4 waves), 2 blocks/CU
    cheby_mfma<<<dim3(512), dim3(256), 0, stream>>>(x, cc, out);
}